// Round 2
// baseline (283.661 us; speedup 1.0000x reference)
//
#include <hip/hip_runtime.h>
#include <hip/hip_bf16.h>

typedef __attribute__((ext_vector_type(8))) short bf16x8;
typedef __attribute__((ext_vector_type(4))) float f32x4;
typedef unsigned short u16;
typedef unsigned int u32;

#define LHS_STRIDE 8421376   // 16*514*1024 floats per stack slot
#define RHS_STRIDE 524288    // 512*1024 floats per stack slot
#define TBL_SPLIT  8224      // 16*514
#define AN 257               // sequence length
#define KSD 68               // K LDS row stride (bf16): 136B = 34 banks -> ~2-way (free)
#define VSD 292              // V^T LDS row stride (584B = 18 banks offset/row -> ~2-way)
#define PSD 292              // P LDS row stride
#define GSD 40               // gemm LDS row stride (80B = 20 banks/row -> 2-way, was 16 -> 8-way)

// row pointer into the concatenated [lhs | rhs] table for stack slot s
__device__ __forceinline__ const float* tbl_row(int s, int g,
    const float* __restrict__ lhs, const float* __restrict__ rhs) {
  if (g < TBL_SPLIT) return lhs + (size_t)s * LHS_STRIDE + (size_t)g * 1024;
  return rhs + (size_t)s * RHS_STRIDE + (size_t)(g - TBL_SPLIT) * 1024;
}

__device__ __forceinline__ u16 f2b(float x) {
  union { __hip_bfloat16 b; u16 u; } c;
  c.b = __float2bfloat16(x);
  return c.u;
}

__device__ __forceinline__ bf16x8 mk8(ushort4 a, ushort4 b) {
  bf16x8 r;
  r[0] = (short)a.x; r[1] = (short)a.y; r[2] = (short)a.z; r[3] = (short)a.w;
  r[4] = (short)b.x; r[5] = (short)b.y; r[6] = (short)b.z; r[7] = (short)b.w;
  return r;
}

struct __align__(16) AttnSmem {
  int idx[260];            // 1040 B
  u16 K[272 * KSD];        // 36992 B  (rows 257..271 stay zero)
  u16 VT[64 * VSD];        // 37376 B  (keys >= 257 stay zero)
  u16 P[4 * 16 * PSD];     // 37376 B  (per-wave 16 rows; cols 272..287 stay zero)
};                         // total 112784 B < 160 KiB

// One block per (b,h): gather-fused attention (whole 257-key score row in regs).
// 4 waves x 16 query rows x 5 iterations covers 257 rows.
__global__ __launch_bounds__(256, 1) void attn_kernel(
    const int* __restrict__ gidx, const float* __restrict__ lhs,
    const float* __restrict__ rhs, u16* __restrict__ attn_out) {
  __shared__ AttnSmem sm;
  const int bh = blockIdx.x, b = bh >> 4, h = bh & 15;
  const int t = threadIdx.x, wave = t >> 6, lane = t & 63;
  const int lg = lane >> 4, lr = lane & 15;

  {  // zero K/VT/P (covers all padding/tail regions)
    u32* p = (u32*)sm.K;
    const int nw = (272 * KSD + 64 * VSD + 4 * 16 * PSD) / 2;
    for (int i = t; i < nw; i += 256) p[i] = 0u;
  }
  for (int i = t; i < AN; i += 256) sm.idx[i] = gidx[b * AN + i];
  __syncthreads();

  // ---- stage K (row-major, bf16) and V^T (transposed, bf16), gather fused
  {
    const int sr = t >> 4, c4 = (t & 15) * 4;
    for (int pass = 0; pass < 17; ++pass) {
      int r = pass * 16 + sr;
      if (r < AN) {
        int g = sm.idx[r];
        float4 kv = *(const float4*)(tbl_row(2, g, lhs, rhs) + h * 64 + c4);
        *(ushort4*)&sm.K[r * KSD + c4] =
            make_ushort4(f2b(kv.x), f2b(kv.y), f2b(kv.z), f2b(kv.w));
        float4 vv = *(const float4*)(tbl_row(3, g, lhs, rhs) + h * 64 + c4);
        sm.VT[(c4 + 0) * VSD + r] = f2b(vv.x);
        sm.VT[(c4 + 1) * VSD + r] = f2b(vv.y);
        sm.VT[(c4 + 2) * VSD + r] = f2b(vv.z);
        sm.VT[(c4 + 3) * VSD + r] = f2b(vv.w);
      }
    }
  }
  __syncthreads();

  u16* Pw = sm.P + wave * 16 * PSD;
  for (int iter = 0; iter < 5; ++iter) {
    const int r0 = iter * 64 + wave * 16;

    // ---- Q fragments (A-operand): row = lr, d = kf*32 + lg*8 + j, scaled by 1/8
    bf16x8 qa[2];
    {
      int qrow = r0 + lr;
      int g = sm.idx[qrow < AN ? qrow : 0];
      const float* qp = tbl_row(1, g, lhs, rhs) + h * 64 + lg * 8;
#pragma unroll
      for (int kf = 0; kf < 2; ++kf) {
        float4 v0 = *(const float4*)(qp + kf * 32);
        float4 v1 = *(const float4*)(qp + kf * 32 + 4);
        bf16x8 a;
        a[0] = (short)f2b(0.125f * v0.x); a[1] = (short)f2b(0.125f * v0.y);
        a[2] = (short)f2b(0.125f * v0.z); a[3] = (short)f2b(0.125f * v0.w);
        a[4] = (short)f2b(0.125f * v1.x); a[5] = (short)f2b(0.125f * v1.y);
        a[6] = (short)f2b(0.125f * v1.z); a[7] = (short)f2b(0.125f * v1.w);
        qa[kf] = a;
      }
    }

    // ---- QK^T: 17 n-frags of 16 keys, K=64 in two MFMA k-steps
    f32x4 s[17];
#pragma unroll
    for (int nf = 0; nf < 17; ++nf) {
      const u16* kp = &sm.K[(nf * 16 + lr) * KSD + lg * 8];
      ushort4 x0 = *(const ushort4*)kp;
      ushort4 x1 = *(const ushort4*)(kp + 4);
      ushort4 y0 = *(const ushort4*)(kp + 32);
      ushort4 y1 = *(const ushort4*)(kp + 36);
      f32x4 acc = {0.f, 0.f, 0.f, 0.f};
      acc = __builtin_amdgcn_mfma_f32_16x16x32_bf16(qa[0], mk8(x0, x1), acc, 0, 0, 0);
      acc = __builtin_amdgcn_mfma_f32_16x16x32_bf16(qa[1], mk8(y0, y1), acc, 0, 0, 0);
      s[nf] = acc;
    }
    // mask cols >= 257 (nf=16 covers 256..271; only col 256 i.e. lr==0 is real)
    if (lr != 0) { s[16][0] = -1e30f; s[16][1] = -1e30f; s[16][2] = -1e30f; s[16][3] = -1e30f; }

    // ---- softmax over keys, per output row (row = lg*4+reg, cols across lr group)
    float inv[4];
#pragma unroll
    for (int reg = 0; reg < 4; ++reg) {
      float m = -1e30f;
#pragma unroll
      for (int nf = 0; nf < 17; ++nf) m = fmaxf(m, s[nf][reg]);
#pragma unroll
      for (int off = 1; off < 16; off <<= 1) m = fmaxf(m, __shfl_xor(m, off, 16));
      float sum = 0.f;
#pragma unroll
      for (int nf = 0; nf < 17; ++nf) {
        float w = __expf(s[nf][reg] - m);
        s[nf][reg] = w;
        sum += w;
      }
#pragma unroll
      for (int off = 1; off < 16; off <<= 1) sum += __shfl_xor(sum, off, 16);
      inv[reg] = 1.0f / sum;
    }
    // ---- write P (C-layout -> A-layout via per-wave LDS round-trip; wave-private,
    //      so no block barrier needed — compiler's lgkmcnt ordering suffices)
#pragma unroll
    for (int reg = 0; reg < 4; ++reg) {
#pragma unroll
      for (int nf = 0; nf < 17; ++nf)
        Pw[(lg * 4 + reg) * PSD + nf * 16 + lr] = f2b(s[nf][reg] * inv[reg]);
    }

    // ---- P x V: out[16 rows][64 d], K=288 keys (zeros past 256)
    f32x4 zero = {0.f, 0.f, 0.f, 0.f};
    f32x4 o[4] = {zero, zero, zero, zero};
#pragma unroll
    for (int ks = 0; ks < 9; ++ks) {
      const u16* pp = &Pw[lr * PSD + ks * 32 + lg * 8];
      bf16x8 pa = mk8(*(const ushort4*)pp, *(const ushort4*)(pp + 4));
#pragma unroll
      for (int nd = 0; nd < 4; ++nd) {
        const u16* vp = &sm.VT[(nd * 16 + lr) * VSD + ks * 32 + lg * 8];
        bf16x8 vb = mk8(*(const ushort4*)vp, *(const ushort4*)(vp + 4));
        o[nd] = __builtin_amdgcn_mfma_f32_16x16x32_bf16(pa, vb, o[nd], 0, 0, 0);
      }
    }

    // ---- store attn tile as bf16 into ws [4112][1024]
#pragma unroll
    for (int nd = 0; nd < 4; ++nd)
#pragma unroll
      for (int reg = 0; reg < 4; ++reg) {
        int row = r0 + lg * 4 + reg;
        if (row < AN)
          attn_out[(size_t)(b * AN + row) * 1024 + h * 64 + nd * 16 + lr] =
              f2b(o[nd][reg]);
      }
  }
}

// Wo f32 -> bf16
__global__ void cvt_wo_kernel(const float* __restrict__ w, u16* __restrict__ o) {
  int i = blockIdx.x * 256 + threadIdx.x;  // indexes float4 groups, 262144 total
  float4 v = ((const float4*)w)[i];
  ((ushort4*)o)[i] = make_ushort4(f2b(v.x), f2b(v.y), f2b(v.z), f2b(v.w));
}

// out[4112][1024] = attn(bf16) x Wo(bf16)^T + bo + hidden(gathered), f32 out
__global__ __launch_bounds__(256, 1) void gemm_kernel(
    const u16* __restrict__ A, const u16* __restrict__ Bw,
    const float* __restrict__ bo, const int* __restrict__ gidx,
    const float* __restrict__ lhs, const float* __restrict__ rhs,
    float* __restrict__ out) {
  __shared__ __align__(16) u16 As[128 * GSD];
  __shared__ __align__(16) u16 Bs[128 * GSD];
  const int t = threadIdx.x, wave = t >> 6, lane = t & 63;
  const int lg = lane >> 4, lr = lane & 15;
  const int mt = blockIdx.x >> 3, nt = blockIdx.x & 7;
  const int m0 = mt * 128, n0 = nt * 128;
  const int wm = wave >> 1, wn = wave & 1;

  f32x4 zero = {0.f, 0.f, 0.f, 0.f};
  f32x4 acc[4][4];
#pragma unroll
  for (int i = 0; i < 4; ++i)
#pragma unroll
    for (int j = 0; j < 4; ++j) acc[i][j] = zero;

  const int srow = t >> 2, scol = (t & 3) * 8;  // 256 threads x 2 passes cover 128x32
  for (int kt = 0; kt < 32; ++kt) {
    const int k0 = kt * 32;
#pragma unroll
    for (int p = 0; p < 2; ++p) {
      int row = srow + p * 64;
      int gar = m0 + row; if (gar > 4111) gar = 4111;   // clamp; masked at store
      uint4 va = *(const uint4*)(A + (size_t)gar * 1024 + k0 + scol);
      *(uint4*)&As[row * GSD + scol] = va;
      uint4 vb = *(const uint4*)(Bw + (size_t)(n0 + row) * 1024 + k0 + scol);
      *(uint4*)&Bs[row * GSD + scol] = vb;
    }
    __syncthreads();
    bf16x8 af[4], bfr[4];
#pragma unroll
    for (int i = 0; i < 4; ++i) {
      af[i]  = *(const bf16x8*)&As[(wm * 64 + i * 16 + lr) * GSD + lg * 8];
      bfr[i] = *(const bf16x8*)&Bs[(wn * 64 + i * 16 + lr) * GSD + lg * 8];
    }
#pragma unroll
    for (int i = 0; i < 4; ++i)
#pragma unroll
      for (int j = 0; j < 4; ++j)
        acc[i][j] = __builtin_amdgcn_mfma_f32_16x16x32_bf16(af[i], bfr[j], acc[i][j], 0, 0, 0);
    __syncthreads();
  }

  // epilogue: residual (gathered hidden) + bias
#pragma unroll
  for (int i = 0; i < 4; ++i)
#pragma unroll
    for (int j = 0; j < 4; ++j)
#pragma unroll
      for (int reg = 0; reg < 4; ++reg) {
        int row = m0 + wm * 64 + i * 16 + lg * 4 + reg;
        int col = n0 + wn * 64 + j * 16 + lr;
        if (row < 4112) {
          int g = gidx[row];
          out[(size_t)row * 1024 + col] =
              tbl_row(0, g, lhs, rhs)[col] + bo[col] + acc[i][j][reg];
        }
      }
}

extern "C" void kernel_launch(void* const* d_in, const int* in_sizes, int n_in,
                              void* d_out, int out_size, void* d_ws, size_t ws_size,
                              hipStream_t stream) {
  const int*   gidx = (const int*)d_in[0];
  const float* lhs  = (const float*)d_in[1];
  const float* rhs  = (const float*)d_in[2];
  const float* Wo   = (const float*)d_in[3];
  const float* bo   = (const float*)d_in[4];
  float* out = (float*)d_out;

  u16* attn_ws = (u16*)d_ws;                       // 4112*1024 bf16 = 8.42 MB
  u16* wo_bf   = attn_ws + (size_t)4112 * 1024;    // 1024*1024 bf16 = 2.10 MB

  cvt_wo_kernel<<<1024, 256, 0, stream>>>(Wo, wo_bf);
  attn_kernel<<<256, 256, 0, stream>>>(gidx, lhs, rhs, attn_ws);
  gemm_kernel<<<264, 256, 0, stream>>>(attn_ws, wo_bf, bo, gidx, lhs, rhs, out);
}

// Round 3
// 262.915 us; speedup vs baseline: 1.0789x; 1.0789x over previous
//
#include <hip/hip_runtime.h>
#include <hip/hip_bf16.h>

typedef __attribute__((ext_vector_type(8))) short bf16x8;
typedef __attribute__((ext_vector_type(4))) float f32x4;
typedef unsigned short u16;
typedef unsigned int u32;

#define LHS_STRIDE 8421376   // 16*514*1024 floats per stack slot
#define RHS_STRIDE 524288    // 512*1024 floats per stack slot
#define TBL_SPLIT  8224      // 16*514
#define AN 257               // sequence length
#define KSD 68               // K LDS row stride (bf16): 136B/row -> ~2-way banks (free)
#define VSD 292              // V^T LDS row stride
#define PSD 292              // P LDS row stride

// row pointer into the concatenated [lhs | rhs] table for stack slot s
__device__ __forceinline__ const float* tbl_row(int s, int g,
    const float* __restrict__ lhs, const float* __restrict__ rhs) {
  if (g < TBL_SPLIT) return lhs + (size_t)s * LHS_STRIDE + (size_t)g * 1024;
  return rhs + (size_t)s * RHS_STRIDE + (size_t)(g - TBL_SPLIT) * 1024;
}

__device__ __forceinline__ u16 f2b(float x) {
  union { __hip_bfloat16 b; u16 u; } c;
  c.b = __float2bfloat16(x);
  return c.u;
}

__device__ __forceinline__ bf16x8 mk8(ushort4 a, ushort4 b) {
  bf16x8 r;
  r[0] = (short)a.x; r[1] = (short)a.y; r[2] = (short)a.z; r[3] = (short)a.w;
  r[4] = (short)b.x; r[5] = (short)b.y; r[6] = (short)b.z; r[7] = (short)b.w;
  return r;
}

// async global->LDS, 16B per lane; LDS dest = wave-uniform base + lane*16
__device__ __forceinline__ void gload16(const u16* g, u16* l) {
  __builtin_amdgcn_global_load_lds((const __attribute__((address_space(1))) void*)g,
                                   (__attribute__((address_space(3))) void*)l,
                                   16, 0, 0);
}

struct __align__(16) AttnSmem {
  int idx[260];            // 1040 B
  u16 K[272 * KSD];        // 36992 B  (rows 257..271 garbage-OK: masked after MFMA)
  u16 VT[64 * VSD];        // 37376 B  (keys >= 257 zeroed)
  u16 P[8 * 16 * PSD];     // 74752 B  (per-wave 16 rows; cols 272+ zeroed)
};                         // total 150160 B < 160 KiB

// One block per (b,h), 8 waves; wave w handles query row-tiles {w, w+8, (w==0: 16)}.
__global__ __launch_bounds__(512, 1) void attn_kernel(
    const int* __restrict__ gidx, const float* __restrict__ lhs,
    const float* __restrict__ rhs, u16* __restrict__ attn_out) {
  __shared__ AttnSmem sm;
  const int bh = blockIdx.x, b = bh >> 4, h = bh & 15;
  const int t = threadIdx.x, wave = t >> 6, lane = t & 63;
  const int lg = lane >> 4, lr = lane & 15;

  {  // zero VT + P (contiguous, 16B-aligned region); K tail needs no zeroing
    uint4 z = {0u, 0u, 0u, 0u};
    uint4* p = (uint4*)sm.VT;
    const int n16 = (64 * VSD + 8 * 16 * PSD) * 2 / 16;  // 7008
    for (int i = t; i < n16; i += 512) p[i] = z;
  }
  for (int i = t; i < AN; i += 512) sm.idx[i] = gidx[b * AN + i];
  __syncthreads();

  // ---- stage K (row-major, bf16) and V^T (transposed, bf16), gather fused
  {
    const int sr = t >> 4, c4 = (t & 15) * 4;
    for (int pass = 0; pass < 9; ++pass) {
      int r = pass * 32 + sr;
      if (r < AN) {
        int g = sm.idx[r];
        float4 kv = *(const float4*)(tbl_row(2, g, lhs, rhs) + h * 64 + c4);
        *(ushort4*)&sm.K[r * KSD + c4] =
            make_ushort4(f2b(kv.x), f2b(kv.y), f2b(kv.z), f2b(kv.w));
        float4 vv = *(const float4*)(tbl_row(3, g, lhs, rhs) + h * 64 + c4);
        sm.VT[(c4 + 0) * VSD + r] = f2b(vv.x);
        sm.VT[(c4 + 1) * VSD + r] = f2b(vv.y);
        sm.VT[(c4 + 2) * VSD + r] = f2b(vv.z);
        sm.VT[(c4 + 3) * VSD + r] = f2b(vv.w);
      }
    }
  }
  __syncthreads();

  u16* Pw = sm.P + wave * 16 * PSD;
  for (int rt = wave; rt < 17; rt += 8) {
    const int r0 = rt * 16;

    // ---- Q fragments (A-operand): row = lr, d = kf*32 + lg*8 + j, scaled by 1/8
    bf16x8 qa[2];
    {
      int qrow = r0 + lr;
      int g = sm.idx[qrow < AN ? qrow : 0];
      const float* qp = tbl_row(1, g, lhs, rhs) + h * 64 + lg * 8;
#pragma unroll
      for (int kf = 0; kf < 2; ++kf) {
        float4 v0 = *(const float4*)(qp + kf * 32);
        float4 v1 = *(const float4*)(qp + kf * 32 + 4);
        bf16x8 a;
        a[0] = (short)f2b(0.125f * v0.x); a[1] = (short)f2b(0.125f * v0.y);
        a[2] = (short)f2b(0.125f * v0.z); a[3] = (short)f2b(0.125f * v0.w);
        a[4] = (short)f2b(0.125f * v1.x); a[5] = (short)f2b(0.125f * v1.y);
        a[6] = (short)f2b(0.125f * v1.z); a[7] = (short)f2b(0.125f * v1.w);
        qa[kf] = a;
      }
    }

    // ---- QK^T: 17 n-frags of 16 keys, K=64 in two MFMA k-steps
    f32x4 s[17];
#pragma unroll
    for (int nf = 0; nf < 17; ++nf) {
      const u16* kp = &sm.K[(nf * 16 + lr) * KSD + lg * 8];
      ushort4 x0 = *(const ushort4*)kp;
      ushort4 x1 = *(const ushort4*)(kp + 4);
      ushort4 y0 = *(const ushort4*)(kp + 32);
      ushort4 y1 = *(const ushort4*)(kp + 36);
      f32x4 acc = {0.f, 0.f, 0.f, 0.f};
      acc = __builtin_amdgcn_mfma_f32_16x16x32_bf16(qa[0], mk8(x0, x1), acc, 0, 0, 0);
      acc = __builtin_amdgcn_mfma_f32_16x16x32_bf16(qa[1], mk8(y0, y1), acc, 0, 0, 0);
      s[nf] = acc;
    }
    // mask cols >= 257 (nf=16 covers 256..271; only col 256 i.e. lr==0 is real)
    if (lr != 0) { s[16][0] = -1e30f; s[16][1] = -1e30f; s[16][2] = -1e30f; s[16][3] = -1e30f; }

    // ---- softmax over keys, per output row (row = lg*4+reg, cols across lr group)
    float inv[4];
#pragma unroll
    for (int reg = 0; reg < 4; ++reg) {
      float m = -1e30f;
#pragma unroll
      for (int nf = 0; nf < 17; ++nf) m = fmaxf(m, s[nf][reg]);
#pragma unroll
      for (int off = 1; off < 16; off <<= 1) m = fmaxf(m, __shfl_xor(m, off, 16));
      float sum = 0.f;
#pragma unroll
      for (int nf = 0; nf < 17; ++nf) {
        float w = __expf(s[nf][reg] - m);
        s[nf][reg] = w;
        sum += w;
      }
#pragma unroll
      for (int off = 1; off < 16; off <<= 1) sum += __shfl_xor(sum, off, 16);
      inv[reg] = 1.0f / sum;
    }
    // ---- write P (C-layout -> A-layout via per-wave LDS round-trip; wave-private)
#pragma unroll
    for (int reg = 0; reg < 4; ++reg) {
#pragma unroll
      for (int nf = 0; nf < 17; ++nf)
        Pw[(lg * 4 + reg) * PSD + nf * 16 + lr] = f2b(s[nf][reg] * inv[reg]);
    }

    // ---- P x V: out[16 rows][64 d], K=288 keys (zeros past 256)
    f32x4 zero = {0.f, 0.f, 0.f, 0.f};
    f32x4 o[4] = {zero, zero, zero, zero};
#pragma unroll
    for (int ks = 0; ks < 9; ++ks) {
      const u16* pp = &Pw[lr * PSD + ks * 32 + lg * 8];
      bf16x8 pa = mk8(*(const ushort4*)pp, *(const ushort4*)(pp + 4));
#pragma unroll
      for (int nd = 0; nd < 4; ++nd) {
        const u16* vp = &sm.VT[(nd * 16 + lr) * VSD + ks * 32 + lg * 8];
        bf16x8 vb = mk8(*(const ushort4*)vp, *(const ushort4*)(vp + 4));
        o[nd] = __builtin_amdgcn_mfma_f32_16x16x32_bf16(pa, vb, o[nd], 0, 0, 0);
      }
    }

    // ---- store attn tile as bf16 into ws [4112][1024]
#pragma unroll
    for (int nd = 0; nd < 4; ++nd)
#pragma unroll
      for (int reg = 0; reg < 4; ++reg) {
        int row = r0 + lg * 4 + reg;
        if (row < AN)
          attn_out[(size_t)(b * AN + row) * 1024 + h * 64 + nd * 16 + lr] =
              f2b(o[nd][reg]);
      }
  }
}

// Wo f32 -> bf16
__global__ void cvt_wo_kernel(const float* __restrict__ w, u16* __restrict__ o) {
  int i = blockIdx.x * 256 + threadIdx.x;  // indexes float4 groups, 262144 total
  float4 v = ((const float4*)w)[i];
  ((ushort4*)o)[i] = make_ushort4(f2b(v.x), f2b(v.y), f2b(v.z), f2b(v.w));
}

// out[4112][1024] = attn(bf16) x Wo(bf16)^T + bo + hidden(gathered), f32 out
// m97-style: global_load_lds width-16 staging, linear LDS + source/read XOR swizzle.
// Swizzle (BK=32, 4x16B slots/row): LDS slot q of row r holds global col-group
// q ^ ((r>>1)&3); bank start = 16*(r&1) + 4*(q) spreads over 8 values -> 2-way (free).
__global__ __launch_bounds__(256, 1) void gemm_kernel(
    const u16* __restrict__ A, const u16* __restrict__ Bw,
    const float* __restrict__ bo, const int* __restrict__ gidx,
    const float* __restrict__ lhs, const float* __restrict__ rhs,
    float* __restrict__ out) {
  __shared__ __align__(16) u16 As[128 * 32];
  __shared__ __align__(16) u16 Bs[128 * 32];
  const int t = threadIdx.x, wave = t >> 6, lane = t & 63;
  const int lg = lane >> 4, lr = lane & 15;
  const int mt = blockIdx.x >> 3, nt = blockIdx.x & 7;
  const int m0 = mt * 128, n0 = nt * 128;
  const int wm = wave >> 1, wn = wave & 1;

  f32x4 zero = {0.f, 0.f, 0.f, 0.f};
  f32x4 acc[4][4];
#pragma unroll
  for (int i = 0; i < 4; ++i)
#pragma unroll
    for (int j = 0; j < 4; ++j) acc[i][j] = zero;

  // staging: wave covers rows wave*32 + i*16 + (lane>>2), global col pre-swizzled
  const int srow = lane >> 2;
  const int scol = (((lane & 3) ^ ((lane >> 3) & 3))) * 8;  // swizzled col-group
  const int ss = (lg ^ ((lr >> 1) & 3)) * 8;                // swizzled read slot

  for (int kt = 0; kt < 32; ++kt) {
    const int k0 = kt * 32;
#pragma unroll
    for (int i = 0; i < 2; ++i) {
      int row = wave * 32 + i * 16 + srow;
      int arow = m0 + row; if (arow > 4111) arow = 4111;   // clamp; masked at store
      gload16(A + (size_t)arow * 1024 + k0 + scol, &As[wave * 1024 + i * 512]);
      gload16(Bw + (size_t)(n0 + row) * 1024 + k0 + scol, &Bs[wave * 1024 + i * 512]);
    }
    __syncthreads();   // compiler drains vmcnt(0) before barrier (m97 semantics)
    bf16x8 af[4], bfr[4];
#pragma unroll
    for (int i = 0; i < 4; ++i) {
      af[i]  = *(const bf16x8*)&As[(wm * 64 + i * 16 + lr) * 32 + ss];
      bfr[i] = *(const bf16x8*)&Bs[(wn * 64 + i * 16 + lr) * 32 + ss];
    }
#pragma unroll
    for (int i = 0; i < 4; ++i)
#pragma unroll
      for (int j = 0; j < 4; ++j)
        acc[i][j] = __builtin_amdgcn_mfma_f32_16x16x32_bf16(af[i], bfr[j], acc[i][j], 0, 0, 0);
    __syncthreads();
  }

  // epilogue: residual (gathered hidden) + bias
#pragma unroll
  for (int i = 0; i < 4; ++i)
#pragma unroll
    for (int j = 0; j < 4; ++j)
#pragma unroll
      for (int reg = 0; reg < 4; ++reg) {
        int row = m0 + wm * 64 + i * 16 + lg * 4 + reg;
        int col = n0 + wn * 64 + j * 16 + lr;
        if (row < 4112) {
          int g = gidx[row];
          out[(size_t)row * 1024 + col] =
              tbl_row(0, g, lhs, rhs)[col] + bo[col] + acc[i][j][reg];
        }
      }
}

extern "C" void kernel_launch(void* const* d_in, const int* in_sizes, int n_in,
                              void* d_out, int out_size, void* d_ws, size_t ws_size,
                              hipStream_t stream) {
  const int*   gidx = (const int*)d_in[0];
  const float* lhs  = (const float*)d_in[1];
  const float* rhs  = (const float*)d_in[2];
  const float* Wo   = (const float*)d_in[3];
  const float* bo   = (const float*)d_in[4];
  float* out = (float*)d_out;

  u16* attn_ws = (u16*)d_ws;                       // 4112*1024 bf16 = 8.42 MB
  u16* wo_bf   = attn_ws + (size_t)4112 * 1024;    // 1024*1024 bf16 = 2.10 MB

  cvt_wo_kernel<<<1024, 256, 0, stream>>>(Wo, wo_bf);
  attn_kernel<<<256, 512, 0, stream>>>(gidx, lhs, rhs, attn_ws);
  gemm_kernel<<<264, 256, 0, stream>>>(attn_ws, wo_bf, bo, gidx, lhs, rhs, out);
}